// Round 2
// baseline (639.448 us; speedup 1.0000x reference)
//
#include <hip/hip_runtime.h>
#include <hip/hip_bf16.h>

#define LSLOPE 0.2f

// ---------------- CSR build ----------------
__global__ void hist_kernel(const int* __restrict__ dst, int E, int N, int* __restrict__ counts) {
    int e = blockIdx.x * blockDim.x + threadIdx.x;
    int ET = E + N;
    if (e < ET) {
        int d = (e < E) ? dst[e] : (e - E);
        atomicAdd(&counts[d], 1);
    }
}

__global__ void scan_kernel(const int* __restrict__ counts, int* __restrict__ offs,
                            int* __restrict__ cursor, int N) {
    __shared__ int part[1024];
    int t = threadIdx.x;
    int CH = (N + 1023) / 1024;
    int base = t * CH;
    int sum = 0;
    for (int k = 0; k < CH; ++k) {
        int idx = base + k;
        if (idx < N) sum += counts[idx];
    }
    part[t] = sum;
    __syncthreads();
    for (int o = 1; o < 1024; o <<= 1) {
        int v = (t >= o) ? part[t - o] : 0;
        __syncthreads();
        part[t] += v;
        __syncthreads();
    }
    int run = (t == 0) ? 0 : part[t - 1];
    for (int k = 0; k < CH; ++k) {
        int idx = base + k;
        if (idx < N) {
            offs[idx] = run;
            cursor[idx] = run;
            run += counts[idx];
        }
    }
    if (t == 1023) offs[N] = run;
}

__global__ void scatter_kernel(const int* __restrict__ src, const int* __restrict__ dst,
                               int E, int N, int* __restrict__ cursor, int* __restrict__ srcs) {
    int e = blockIdx.x * blockDim.x + threadIdx.x;
    int ET = E + N;
    if (e < ET) {
        int d, s;
        if (e < E) { d = dst[e]; s = src[e]; }
        else { d = e - E; s = d; }
        int pos = atomicAdd(&cursor[d], 1);
        srcs[pos] = s;
    }
}

// ---------------- GEMM: C[M,N] = A[M,K] @ B[K,N], f32 ----------------
__global__ void gemm64(const float* __restrict__ A, const float* __restrict__ B,
                       float* __restrict__ C, int M, int N, int K) {
    __shared__ float As[64][17];
    __shared__ float Bs[16][65];
    int tx = threadIdx.x, ty = threadIdx.y;   // 16 x 16
    int tid = ty * 16 + tx;
    int bm = blockIdx.y * 64, bn = blockIdx.x * 64;
    float acc[4][4] = {};
    for (int k0 = 0; k0 < K; k0 += 16) {
        #pragma unroll
        for (int i = 0; i < 4; ++i) {
            int idx = tid + i * 256;          // 64x16 A tile
            int r = idx >> 4, c = idx & 15;
            int gr = bm + r;
            As[r][c] = (gr < M) ? A[(size_t)gr * K + k0 + c] : 0.f;
        }
        #pragma unroll
        for (int i = 0; i < 4; ++i) {
            int idx = tid + i * 256;          // 16x64 B tile
            int r = idx >> 6, c = idx & 63;
            Bs[r][c] = B[(size_t)(k0 + r) * N + bn + c];
        }
        __syncthreads();
        #pragma unroll
        for (int k = 0; k < 16; ++k) {
            float a[4], b[4];
            #pragma unroll
            for (int i = 0; i < 4; ++i) a[i] = As[ty * 4 + i][k];
            #pragma unroll
            for (int j = 0; j < 4; ++j) b[j] = Bs[k][tx * 4 + j];
            #pragma unroll
            for (int i = 0; i < 4; ++i)
                #pragma unroll
                for (int j = 0; j < 4; ++j) acc[i][j] += a[i] * b[j];
        }
        __syncthreads();
    }
    #pragma unroll
    for (int i = 0; i < 4; ++i) {
        int r = bm + ty * 4 + i;
        if (r < M) {
            #pragma unroll
            for (int j = 0; j < 4; ++j)
                C[(size_t)r * N + bn + tx * 4 + j] = acc[i][j];
        }
    }
}

// ---------------- Layer-1 GATv2: per-node block (8 heads x 64 ch) ----------------
__global__ void gat_l1(const float* __restrict__ xl, const float* __restrict__ xr,
                       const int* __restrict__ offs, const int* __restrict__ srcs,
                       const float* __restrict__ att, const float* __restrict__ bias,
                       float* __restrict__ h1, int Nn) {
    int i = blockIdx.x;
    int t = threadIdx.x;                       // 0..255
    int ch0 = t, ch1 = t + 256;                // head = t/64 and 4 + t/64, c = t%64
    float xrv0 = xr[(size_t)i * 512 + ch0];
    float xrv1 = xr[(size_t)i * 512 + ch1];
    float at0 = att[ch0];
    float at1 = att[ch1];
    float m0 = -1e30f, m1 = -1e30f, d0 = 0.f, d1 = 0.f, a0 = 0.f, a1 = 0.f;
    int kb = offs[i], ke = offs[i + 1];
    for (int k = kb; k < ke; ++k) {
        int j = srcs[k];
        float v0 = xl[(size_t)j * 512 + ch0];
        float v1 = xl[(size_t)j * 512 + ch1];
        float p0 = v0 + xrv0; p0 = (p0 > 0.f ? p0 : LSLOPE * p0) * at0;
        float p1 = v1 + xrv1; p1 = (p1 > 0.f ? p1 : LSLOPE * p1) * at1;
        #pragma unroll
        for (int msk = 32; msk >= 1; msk >>= 1) {
            p0 += __shfl_xor(p0, msk, 64);
            p1 += __shfl_xor(p1, msk, 64);
        }
        float nm0 = fmaxf(m0, p0);
        float sc0 = __expf(m0 - nm0), w0 = __expf(p0 - nm0);
        d0 = d0 * sc0 + w0; a0 = a0 * sc0 + w0 * v0; m0 = nm0;
        float nm1 = fmaxf(m1, p1);
        float sc1 = __expf(m1 - nm1), w1 = __expf(p1 - nm1);
        d1 = d1 * sc1 + w1; a1 = a1 * sc1 + w1 * v1; m1 = nm1;
    }
    float o0 = a0 / d0 + bias[ch0];
    float o1 = a1 / d1 + bias[ch1];
    o0 = o0 > 0.f ? o0 : __expf(o0) - 1.f;     // ELU
    o1 = o1 > 0.f ? o1 : __expf(o1) - 1.f;
    h1[(size_t)i * 512 + ch0] = o0;
    h1[(size_t)i * 512 + ch1] = o1;
}

// ---------------- Layer-2 GATv2: one wave per node (1 head x 64 ch) ----------------
__global__ void gat_l2(const float* __restrict__ xl, const float* __restrict__ xr,
                       const int* __restrict__ offs, const int* __restrict__ srcs,
                       const float* __restrict__ att, const float* __restrict__ bias,
                       float* __restrict__ h2, int Nn) {
    int gid = blockIdx.x * blockDim.x + threadIdx.x;
    int i = gid >> 6;
    int lane = threadIdx.x & 63;
    if (i >= Nn) return;
    float xrv = xr[(size_t)i * 64 + lane];
    float at = att[lane];
    float m = -1e30f, d = 0.f, a = 0.f;
    int kb = offs[i], ke = offs[i + 1];
    for (int k = kb; k < ke; ++k) {
        int j = srcs[k];
        float v = xl[(size_t)j * 64 + lane];
        float p = v + xrv; p = (p > 0.f ? p : LSLOPE * p) * at;
        #pragma unroll
        for (int msk = 32; msk >= 1; msk >>= 1) p += __shfl_xor(p, msk, 64);
        float nm = fmaxf(m, p);
        float sc = __expf(m - nm), w = __expf(p - nm);
        d = d * sc + w; a = a * sc + w * v; m = nm;
    }
    float o = a / d + bias[lane];
    h2[(size_t)i * 64 + lane] = o > 0.f ? o : __expf(o) - 1.f;
}

// ---------------- Final linear 64->32 + ELU, f32 out ----------------
__global__ void final_lin(const float* __restrict__ h2, const float* __restrict__ W,
                          const float* __restrict__ b, float* __restrict__ out, int Nn) {
    __shared__ float Ws[64 * 32];
    __shared__ float bs[32];
    int t = threadIdx.x;
    for (int idx = t; idx < 2048; idx += 256) Ws[idx] = W[idx];
    if (t < 32) bs[t] = b[t];
    __syncthreads();
    int node = blockIdx.x * 8 + (t >> 5);
    int o = t & 31;
    if (node < Nn) {
        const float* hr = &h2[(size_t)node * 64];
        float acc = bs[o];
        #pragma unroll
        for (int k = 0; k < 64; ++k) acc += hr[k] * Ws[k * 32 + o];
        acc = acc > 0.f ? acc : __expf(acc) - 1.f;
        out[(size_t)node * 32 + o] = acc;
    }
}

extern "C" void kernel_launch(void* const* d_in, const int* in_sizes, int n_in,
                              void* d_out, int out_size, void* d_ws, size_t ws_size,
                              hipStream_t stream) {
    const float* x    = (const float*)d_in[0];
    const int*   ei   = (const int*)d_in[1];
    const float* W1l  = (const float*)d_in[2];
    const float* W1r  = (const float*)d_in[3];
    const float* att1 = (const float*)d_in[4];
    const float* b1   = (const float*)d_in[5];
    const float* W2l  = (const float*)d_in[6];
    const float* W2r  = (const float*)d_in[7];
    const float* att2 = (const float*)d_in[8];
    const float* b2   = (const float*)d_in[9];
    const float* Wlin = (const float*)d_in[10];
    const float* blin = (const float*)d_in[11];

    const int N  = in_sizes[0] / 128;   // 20000
    const int E  = in_sizes[1] / 2;     // 320000
    const int ET = E + N;               // + self-loops

    char* w = (char*)d_ws;
    size_t cur = 0;
    auto take = [&](size_t bytes) -> void* {
        void* p = w + cur;
        cur = (cur + bytes + 255) & ~(size_t)255;
        return p;
    };
    int*   counts = (int*)take((size_t)N * 4);
    int*   offs   = (int*)take((size_t)(N + 1) * 4);
    int*   cursor = (int*)take((size_t)N * 4);
    int*   srcs   = (int*)take((size_t)ET * 4);
    float* xl1    = (float*)take((size_t)N * 512 * 4);
    float* xr1    = (float*)take((size_t)N * 512 * 4);
    float* h1     = (float*)take((size_t)N * 512 * 4);
    // Layer-2 buffers overlap the (dead-after-gat_l1) xl1 region: 3 * 5.12MB < 40.96MB
    float* xl2    = xl1;
    float* xr2    = xl1 + (size_t)N * 64;
    float* h2     = xl1 + (size_t)N * 128;

    hipMemsetAsync(counts, 0, (size_t)N * 4, stream);
    hist_kernel<<<(ET + 255) / 256, 256, 0, stream>>>(ei + E, E, N, counts);
    scan_kernel<<<1, 1024, 0, stream>>>(counts, offs, cursor, N);
    scatter_kernel<<<(ET + 255) / 256, 256, 0, stream>>>(ei, ei + E, E, N, cursor, srcs);

    dim3 tb(16, 16);
    // Layer 1 transforms: [N,128] @ [128,512]
    gemm64<<<dim3(512 / 64, (N + 63) / 64), tb, 0, stream>>>(x, W1l, xl1, N, 512, 128);
    gemm64<<<dim3(512 / 64, (N + 63) / 64), tb, 0, stream>>>(x, W1r, xr1, N, 512, 128);
    gat_l1<<<N, 256, 0, stream>>>(xl1, xr1, offs, srcs, att1, b1, h1, N);

    // Layer 2 transforms: [N,512] @ [512,64]  (xl2/xr2 live in xl1's region)
    gemm64<<<dim3(1, (N + 63) / 64), tb, 0, stream>>>(h1, W2l, xl2, N, 64, 512);
    gemm64<<<dim3(1, (N + 63) / 64), tb, 0, stream>>>(h1, W2r, xr2, N, 64, 512);
    gat_l2<<<((size_t)N * 64 + 255) / 256, 256, 0, stream>>>(xl2, xr2, offs, srcs, att2, b2, h2, N);

    final_lin<<<(N + 7) / 8, 256, 0, stream>>>(h2, Wlin, blin, (float*)d_out, N);
}

// Round 3
// 329.200 us; speedup vs baseline: 1.9424x; 1.9424x over previous
//
#include <hip/hip_runtime.h>
#include <hip/hip_bf16.h>

#define LSLOPE 0.2f

typedef __attribute__((ext_vector_type(8))) short short8;
typedef __attribute__((ext_vector_type(4))) float floatx4;

__device__ __forceinline__ float b2f(short s) {
    unsigned u = ((unsigned)(unsigned short)s) << 16;
    float f; __builtin_memcpy(&f, &u, 4); return f;
}
__device__ __forceinline__ short f2b(float f) {
    __hip_bfloat16 hb = __float2bfloat16(f);   // RNE
    unsigned short us; __builtin_memcpy(&us, &hb, 2);
    return (short)us;
}

// ---------------- CSR build ----------------
__global__ void hist_kernel(const int* __restrict__ dst, int E, int N, int* __restrict__ counts) {
    int e = blockIdx.x * blockDim.x + threadIdx.x;
    int ET = E + N;
    if (e < ET) {
        int d = (e < E) ? dst[e] : (e - E);
        atomicAdd(&counts[d], 1);
    }
}

__global__ void scan_kernel(const int* __restrict__ counts, int* __restrict__ offs,
                            int* __restrict__ cursor, int N) {
    __shared__ int part[1024];
    int t = threadIdx.x;
    int CH = (N + 1023) / 1024;
    int base = t * CH;
    int sum = 0;
    for (int k = 0; k < CH; ++k) {
        int idx = base + k;
        if (idx < N) sum += counts[idx];
    }
    part[t] = sum;
    __syncthreads();
    for (int o = 1; o < 1024; o <<= 1) {
        int v = (t >= o) ? part[t - o] : 0;
        __syncthreads();
        part[t] += v;
        __syncthreads();
    }
    int run = (t == 0) ? 0 : part[t - 1];
    for (int k = 0; k < CH; ++k) {
        int idx = base + k;
        if (idx < N) {
            offs[idx] = run;
            cursor[idx] = run;
            run += counts[idx];
        }
    }
    if (t == 1023) offs[N] = run;
}

__global__ void scatter_kernel(const int* __restrict__ src, const int* __restrict__ dst,
                               int E, int N, int* __restrict__ cursor, int* __restrict__ srcs) {
    int e = blockIdx.x * blockDim.x + threadIdx.x;
    int ET = E + N;
    if (e < ET) {
        int d, s;
        if (e < E) { d = dst[e]; s = src[e]; }
        else { d = e - E; s = d; }
        int pos = atomicAdd(&cursor[d], 1);
        srcs[pos] = s;
    }
}

// ---------------- dtype conversions ----------------
__global__ void cvt_f32_bf16(const float* __restrict__ in, short* __restrict__ out, int n) {
    int i = blockIdx.x * blockDim.x + threadIdx.x;
    if (i < n) out[i] = f2b(in[i]);
}

// W [K,N] f32 -> Wt [N,K] bf16
__global__ void transpose_cvt(const float* __restrict__ W, short* __restrict__ Wt, int K, int N) {
    int idx = blockIdx.x * blockDim.x + threadIdx.x;
    if (idx < K * N) {
        int k = idx / N, n = idx % N;
        Wt[(size_t)n * K + k] = f2b(W[idx]);
    }
}

// ---------------- MFMA GEMM: C[M,N] = A[M,K] @ Bt[N,K]^T, bf16 in/out, f32 acc ----
// 64x64 tile, 4 waves; wave w does rows [w*16,w*16+16), 4 col-fragments of 16.
__global__ __launch_bounds__(256) void mfma_gemm(const short* __restrict__ A,
                                                 const short* __restrict__ Bt,
                                                 short* __restrict__ C, int M, int N, int K) {
    __shared__ short As[64 * 40];   // rows padded to 40 shorts (80B) to break bank conflicts
    __shared__ short Bs[64 * 40];
    int t = threadIdx.x;
    int w = t >> 6, L = t & 63;
    int quad = L >> 4, lane15 = L & 15;
    int M0 = blockIdx.y * 64, N0 = blockIdx.x * 64;
    int r = t >> 2, part = t & 3;   // staging: 4 threads per row, 8 bf16 each
    floatx4 acc[4] = {};
    for (int k0 = 0; k0 < K; k0 += 32) {
        short8 av = {};
        int grow = M0 + r;
        if (grow < M) av = *reinterpret_cast<const short8*>(A + (size_t)grow * K + k0 + part * 8);
        *reinterpret_cast<short8*>(&As[r * 40 + part * 8]) = av;
        short8 bv = *reinterpret_cast<const short8*>(Bt + (size_t)(N0 + r) * K + k0 + part * 8);
        *reinterpret_cast<short8*>(&Bs[r * 40 + part * 8]) = bv;
        __syncthreads();
        short8 a = *reinterpret_cast<const short8*>(&As[(w * 16 + lane15) * 40 + quad * 8]);
        #pragma unroll
        for (int tt = 0; tt < 4; ++tt) {
            short8 b = *reinterpret_cast<const short8*>(&Bs[(tt * 16 + lane15) * 40 + quad * 8]);
            acc[tt] = __builtin_amdgcn_mfma_f32_16x16x32_bf16(a, b, acc[tt], 0, 0, 0);
        }
        __syncthreads();
    }
    #pragma unroll
    for (int tt = 0; tt < 4; ++tt) {
        #pragma unroll
        for (int rg = 0; rg < 4; ++rg) {
            int row = M0 + w * 16 + quad * 4 + rg;   // C/D: row = quad*4+reg
            int col = N0 + tt * 16 + lane15;         //      col = lane&15
            if (row < M) C[(size_t)row * N + col] = f2b(acc[tt][rg]);
        }
    }
}

// ---------------- Layer-1 GATv2: one wave per node, 8 ch/lane (head = lane>>3) ----
__global__ void gat_l1(const short* __restrict__ xl, const short* __restrict__ xr,
                       const int* __restrict__ offs, const int* __restrict__ srcs,
                       const float* __restrict__ att, const float* __restrict__ bias,
                       short* __restrict__ h1, int Nn) {
    int i = (blockIdx.x * blockDim.x + threadIdx.x) >> 6;
    if (i >= Nn) return;                       // wave-uniform
    int L = threadIdx.x & 63;
    int c0 = L * 8;
    float xrv[8], at[8];
    {
        short8 x8 = *reinterpret_cast<const short8*>(xr + (size_t)i * 512 + c0);
        #pragma unroll
        for (int c = 0; c < 8; ++c) { xrv[c] = b2f(x8[c]); at[c] = att[c0 + c]; }
    }
    float m = -1e30f, dnm = 0.f;
    float acc[8] = {};
    int kb = offs[i], ke = offs[i + 1];
    for (int k = kb; k < ke; ++k) {
        int j = srcs[k];
        short8 v8 = *reinterpret_cast<const short8*>(xl + (size_t)j * 512 + c0);
        float v[8];
        float p = 0.f;
        #pragma unroll
        for (int c = 0; c < 8; ++c) {
            v[c] = b2f(v8[c]);
            float tv = v[c] + xrv[c];
            float u = 0.6f * tv + 0.4f * fabsf(tv);    // leakyrelu slope 0.2
            p = fmaf(at[c], u, p);
        }
        p += __shfl_xor(p, 1, 64);
        p += __shfl_xor(p, 2, 64);
        p += __shfl_xor(p, 4, 64);                     // head-score in all 8 lanes of group
        float nm = fmaxf(m, p);
        float sc = __expf(m - nm), wgt = __expf(p - nm);
        dnm = dnm * sc + wgt;
        #pragma unroll
        for (int c = 0; c < 8; ++c) acc[c] = acc[c] * sc + wgt * v[c];
        m = nm;
    }
    float inv = 1.f / dnm;
    short8 o8;
    #pragma unroll
    for (int c = 0; c < 8; ++c) {
        float o = acc[c] * inv + bias[c0 + c];
        o = o > 0.f ? o : __expf(o) - 1.f;             // ELU
        o8[c] = f2b(o);
    }
    *reinterpret_cast<short8*>(h1 + (size_t)i * 512 + c0) = o8;
}

// ---------------- Layer-2 GATv2: one wave per node (1 head x 64 ch) ----------------
__global__ void gat_l2(const short* __restrict__ xl, const short* __restrict__ xr,
                       const int* __restrict__ offs, const int* __restrict__ srcs,
                       const float* __restrict__ att, const float* __restrict__ bias,
                       float* __restrict__ h2, int Nn) {
    int i = (blockIdx.x * blockDim.x + threadIdx.x) >> 6;
    if (i >= Nn) return;
    int lane = threadIdx.x & 63;
    float xrv = b2f(xr[(size_t)i * 64 + lane]);
    float at = att[lane];
    float m = -1e30f, d = 0.f, a = 0.f;
    int kb = offs[i], ke = offs[i + 1];
    for (int k = kb; k < ke; ++k) {
        int j = srcs[k];
        float v = b2f(xl[(size_t)j * 64 + lane]);
        float tv = v + xrv;
        float p = at * (0.6f * tv + 0.4f * fabsf(tv));
        #pragma unroll
        for (int msk = 32; msk >= 1; msk >>= 1) p += __shfl_xor(p, msk, 64);
        float nm = fmaxf(m, p);
        float sc = __expf(m - nm), wgt = __expf(p - nm);
        d = d * sc + wgt; a = a * sc + wgt * v; m = nm;
    }
    float o = a / d + bias[lane];
    h2[(size_t)i * 64 + lane] = o > 0.f ? o : __expf(o) - 1.f;
}

// ---------------- Final linear 64->32 + ELU, f32 out ----------------
__global__ void final_lin(const float* __restrict__ h2, const float* __restrict__ W,
                          const float* __restrict__ b, float* __restrict__ out, int Nn) {
    __shared__ float Ws[64 * 32];
    __shared__ float bs[32];
    int t = threadIdx.x;
    for (int idx = t; idx < 2048; idx += 256) Ws[idx] = W[idx];
    if (t < 32) bs[t] = b[t];
    __syncthreads();
    int node = blockIdx.x * 8 + (t >> 5);
    int o = t & 31;
    if (node < Nn) {
        const float* hr = &h2[(size_t)node * 64];
        float acc = bs[o];
        #pragma unroll
        for (int k = 0; k < 64; ++k) acc += hr[k] * Ws[k * 32 + o];
        acc = acc > 0.f ? acc : __expf(acc) - 1.f;
        out[(size_t)node * 32 + o] = acc;
    }
}

extern "C" void kernel_launch(void* const* d_in, const int* in_sizes, int n_in,
                              void* d_out, int out_size, void* d_ws, size_t ws_size,
                              hipStream_t stream) {
    const float* x    = (const float*)d_in[0];
    const int*   ei   = (const int*)d_in[1];
    const float* W1l  = (const float*)d_in[2];
    const float* W1r  = (const float*)d_in[3];
    const float* att1 = (const float*)d_in[4];
    const float* b1   = (const float*)d_in[5];
    const float* W2l  = (const float*)d_in[6];
    const float* W2r  = (const float*)d_in[7];
    const float* att2 = (const float*)d_in[8];
    const float* b2   = (const float*)d_in[9];
    const float* Wlin = (const float*)d_in[10];
    const float* blin = (const float*)d_in[11];

    const int N  = in_sizes[0] / 128;   // 20000
    const int E  = in_sizes[1] / 2;     // 320000
    const int ET = E + N;

    char* w = (char*)d_ws;
    size_t cur = 0;
    auto take = [&](size_t bytes) -> void* {
        void* p = w + cur;
        cur = (cur + bytes + 255) & ~(size_t)255;
        return p;
    };
    int*   counts = (int*)take((size_t)N * 4);
    int*   offs   = (int*)take((size_t)(N + 1) * 4);
    int*   cursor = (int*)take((size_t)N * 4);
    int*   srcs   = (int*)take((size_t)ET * 4);
    short* xb     = (short*)take((size_t)N * 128 * 2);
    short* w1lt   = (short*)take((size_t)512 * 128 * 2);
    short* w1rt   = (short*)take((size_t)512 * 128 * 2);
    short* w2lt   = (short*)take((size_t)64 * 512 * 2);
    short* w2rt   = (short*)take((size_t)64 * 512 * 2);
    short* xl1    = (short*)take((size_t)N * 512 * 2);
    short* xr1    = (short*)take((size_t)N * 512 * 2);
    short* h1     = (short*)take((size_t)N * 512 * 2);
    short* xl2    = (short*)take((size_t)N * 64 * 2);
    short* xr2    = (short*)take((size_t)N * 64 * 2);
    float* h2     = (float*)take((size_t)N * 64 * 4);

    hipMemsetAsync(counts, 0, (size_t)N * 4, stream);
    hist_kernel<<<(ET + 255) / 256, 256, 0, stream>>>(ei + E, E, N, counts);
    scan_kernel<<<1, 1024, 0, stream>>>(counts, offs, cursor, N);
    scatter_kernel<<<(ET + 255) / 256, 256, 0, stream>>>(ei, ei + E, E, N, cursor, srcs);

    cvt_f32_bf16<<<(N * 128 + 255) / 256, 256, 0, stream>>>(x, xb, N * 128);
    transpose_cvt<<<(128 * 512 + 255) / 256, 256, 0, stream>>>(W1l, w1lt, 128, 512);
    transpose_cvt<<<(128 * 512 + 255) / 256, 256, 0, stream>>>(W1r, w1rt, 128, 512);
    transpose_cvt<<<(512 * 64 + 255) / 256, 256, 0, stream>>>(W2l, w2lt, 512, 64);
    transpose_cvt<<<(512 * 64 + 255) / 256, 256, 0, stream>>>(W2r, w2rt, 512, 64);

    int MB = (N + 63) / 64;   // 313
    mfma_gemm<<<dim3(8, MB), 256, 0, stream>>>(xb, w1lt, xl1, N, 512, 128);
    mfma_gemm<<<dim3(8, MB), 256, 0, stream>>>(xb, w1rt, xr1, N, 512, 128);
    gat_l1<<<(N + 3) / 4, 256, 0, stream>>>(xl1, xr1, offs, srcs, att1, b1, h1, N);

    mfma_gemm<<<dim3(1, MB), 256, 0, stream>>>(h1, w2lt, xl2, N, 64, 512);
    mfma_gemm<<<dim3(1, MB), 256, 0, stream>>>(h1, w2rt, xr2, N, 64, 512);
    gat_l2<<<(N + 3) / 4, 256, 0, stream>>>(xl2, xr2, offs, srcs, att2, b2, h2, N);

    final_lin<<<(N + 7) / 8, 256, 0, stream>>>(h2, Wlin, blin, (float*)d_out, N);
}

// Round 4
// 289.340 us; speedup vs baseline: 2.2100x; 1.1378x over previous
//
#include <hip/hip_runtime.h>
#include <hip/hip_bf16.h>

typedef __attribute__((ext_vector_type(8))) short short8;
typedef __attribute__((ext_vector_type(4))) float floatx4;

__device__ __forceinline__ float b2f(short s) {
    unsigned u = ((unsigned)(unsigned short)s) << 16;
    float f; __builtin_memcpy(&f, &u, 4); return f;
}
__device__ __forceinline__ short f2b(float f) {
    __hip_bfloat16 hb = __float2bfloat16(f);   // RNE
    unsigned short us; __builtin_memcpy(&us, &hb, 2);
    return (short)us;
}

// ---------------- CSR build ----------------
__global__ void hist_kernel(const int* __restrict__ dst, int E, int N, int* __restrict__ counts) {
    int e = blockIdx.x * blockDim.x + threadIdx.x;
    int ET = E + N;
    if (e < ET) {
        int d = (e < E) ? dst[e] : (e - E);
        atomicAdd(&counts[d], 1);
    }
}

__global__ void scan_kernel(const int* __restrict__ counts, int* __restrict__ offs,
                            int* __restrict__ cursor, int N) {
    __shared__ int part[1024];
    int t = threadIdx.x;
    int CH = (N + 1023) / 1024;
    int base = t * CH;
    int sum = 0;
    for (int k = 0; k < CH; ++k) {
        int idx = base + k;
        if (idx < N) sum += counts[idx];
    }
    part[t] = sum;
    __syncthreads();
    for (int o = 1; o < 1024; o <<= 1) {
        int v = (t >= o) ? part[t - o] : 0;
        __syncthreads();
        part[t] += v;
        __syncthreads();
    }
    int run = (t == 0) ? 0 : part[t - 1];
    for (int k = 0; k < CH; ++k) {
        int idx = base + k;
        if (idx < N) {
            offs[idx] = run;
            cursor[idx] = run;
            run += counts[idx];
        }
    }
    if (t == 1023) offs[N] = run;
}

__global__ void scatter_kernel(const int* __restrict__ src, const int* __restrict__ dst,
                               int E, int N, int* __restrict__ cursor, int* __restrict__ srcs) {
    int e = blockIdx.x * blockDim.x + threadIdx.x;
    int ET = E + N;
    if (e < ET) {
        int d, s;
        if (e < E) { d = dst[e]; s = src[e]; }
        else { d = e - E; s = d; }
        int pos = atomicAdd(&cursor[d], 1);
        srcs[pos] = s;
    }
}

// ---------------- conversions ----------------
__global__ void cvt_f32_bf16(const float* __restrict__ in, short* __restrict__ out, int n) {
    int i = blockIdx.x * blockDim.x + threadIdx.x;
    if (i < n) out[i] = f2b(in[i]);
}

// All four weight transposes in one dispatch.
// w1t [1024,128]: rows 0-511 = W1l^T, rows 512-1023 = W1r^T (W1 is [128,512])
// w2t [128,512]:  rows 0-63  = W2l^T, rows 64-127  = W2r^T (W2 is [512,64])
__global__ void prep_weights(const float* __restrict__ W1l, const float* __restrict__ W1r,
                             const float* __restrict__ W2l, const float* __restrict__ W2r,
                             short* __restrict__ w1t, short* __restrict__ w2t) {
    int idx = blockIdx.x * blockDim.x + threadIdx.x;
    if (idx < 131072) {
        int n = idx >> 7, k = idx & 127;
        float v = (n < 512) ? W1l[k * 512 + n] : W1r[k * 512 + (n - 512)];
        w1t[idx] = f2b(v);
    } else if (idx < 131072 + 65536) {
        int j = idx - 131072;
        int n = j >> 9, k = j & 511;
        float v = (n < 64) ? W2l[k * 64 + n] : W2r[k * 64 + (n - 64)];
        w2t[j] = f2b(v);
    }
}

// ---------------- GEMM1: C[M,1024] = A[M,128] @ w1t[1024,128]^T ----------------
// 64M x 128N tile, full K=128 staged once: single barrier, 32 MFMA/wave.
__global__ __launch_bounds__(256) void gemm1(const short* __restrict__ A,
                                             const short* __restrict__ Bt,
                                             short* __restrict__ C, int M) {
    __shared__ short As[64 * 136];    // +8 shorts/row pad
    __shared__ short Bs[128 * 136];
    int t = threadIdx.x;
    int w = t >> 6, L = t & 63, q = L >> 4, s = L & 15;
    int M0 = blockIdx.y * 64, N0 = blockIdx.x * 128;
    #pragma unroll
    for (int i = 0; i < 4; ++i) {       // A: 64 rows x 16 chunks of 8
        int c = t + i * 256;
        int r = c >> 4, col = (c & 15) * 8;
        int gr = M0 + r;
        short8 v = {};
        if (gr < M) v = *(const short8*)(A + (size_t)gr * 128 + col);
        *(short8*)(&As[r * 136 + col]) = v;
    }
    #pragma unroll
    for (int i = 0; i < 8; ++i) {       // B: 128 rows x 16 chunks
        int c = t + i * 256;
        int r = c >> 4, col = (c & 15) * 8;
        short8 v = *(const short8*)(Bt + (size_t)(N0 + r) * 128 + col);
        *(short8*)(&Bs[r * 136 + col]) = v;
    }
    __syncthreads();
    short8 a[4];
    #pragma unroll
    for (int kk = 0; kk < 4; ++kk)
        a[kk] = *(const short8*)(&As[(w * 16 + s) * 136 + kk * 32 + q * 8]);
    floatx4 acc[8] = {};
    #pragma unroll
    for (int tt = 0; tt < 8; ++tt) {
        #pragma unroll
        for (int kk = 0; kk < 4; ++kk) {
            short8 b = *(const short8*)(&Bs[(tt * 16 + s) * 136 + kk * 32 + q * 8]);
            acc[tt] = __builtin_amdgcn_mfma_f32_16x16x32_bf16(a[kk], b, acc[tt], 0, 0, 0);
        }
    }
    #pragma unroll
    for (int tt = 0; tt < 8; ++tt) {
        #pragma unroll
        for (int rg = 0; rg < 4; ++rg) {
            int row = M0 + w * 16 + q * 4 + rg;   // C/D: row=quad*4+reg, col=lane&15
            int col = N0 + tt * 16 + s;
            if (row < M) C[(size_t)row * 1024 + col] = f2b(acc[tt][rg]);
        }
    }
}

// ---------------- GEMM2: C[M,128] = h1[M,512] @ w2t[128,512]^T ----------------
// 32M x 128N tile, K-loop of 64. Wave w: rows (w>>1)*16, cols (w&1)*64.
__global__ __launch_bounds__(256) void gemm2(const short* __restrict__ A,
                                             const short* __restrict__ Bt,
                                             short* __restrict__ C, int M) {
    __shared__ short As[32 * 72];
    __shared__ short Bs[128 * 72];
    int t = threadIdx.x;
    int w = t >> 6, L = t & 63, q = L >> 4, s = L & 15;
    int rw = (w >> 1) * 16, cw = (w & 1) * 64;
    int M0 = blockIdx.x * 32;
    floatx4 acc[4] = {};
    for (int k0 = 0; k0 < 512; k0 += 64) {
        {   // A: 32 rows x 8 chunks of 8
            int r = t >> 3, col = (t & 7) * 8;
            int gr = M0 + r;
            short8 v = {};
            if (gr < M) v = *(const short8*)(A + (size_t)gr * 512 + k0 + col);
            *(short8*)(&As[r * 72 + col]) = v;
        }
        #pragma unroll
        for (int i = 0; i < 4; ++i) {   // B: 128 rows x 8 chunks
            int c = t + i * 256;
            int r = c >> 3, col = (c & 7) * 8;
            short8 v = *(const short8*)(Bt + (size_t)r * 512 + k0 + col);
            *(short8*)(&Bs[r * 72 + col]) = v;
        }
        __syncthreads();
        #pragma unroll
        for (int kk = 0; kk < 2; ++kk) {
            short8 a = *(const short8*)(&As[(rw + s) * 72 + kk * 32 + q * 8]);
            #pragma unroll
            for (int tt = 0; tt < 4; ++tt) {
                short8 b = *(const short8*)(&Bs[(cw + tt * 16 + s) * 72 + kk * 32 + q * 8]);
                acc[tt] = __builtin_amdgcn_mfma_f32_16x16x32_bf16(a, b, acc[tt], 0, 0, 0);
            }
        }
        __syncthreads();
    }
    #pragma unroll
    for (int tt = 0; tt < 4; ++tt) {
        #pragma unroll
        for (int rg = 0; rg < 4; ++rg) {
            int row = M0 + rw + q * 4 + rg;
            int col = cw + tt * 16 + s;
            if (row < M) C[(size_t)row * 128 + col] = f2b(acc[tt][rg]);
        }
    }
}

// ---------------- Layer-1 GATv2: one wave/node, 8 ch/lane, no-max softmax, x2 unroll
__global__ void gat_l1(const short* __restrict__ xlr,
                       const int* __restrict__ offs, const int* __restrict__ srcs,
                       const float* __restrict__ att, const float* __restrict__ bias,
                       short* __restrict__ h1, int Nn) {
    int i = (blockIdx.x * blockDim.x + threadIdx.x) >> 6;
    if (i >= Nn) return;
    int L = threadIdx.x & 63;
    int c0 = L * 8;
    float xrv[8], at[8];
    {
        short8 x8 = *(const short8*)(xlr + (size_t)i * 1024 + 512 + c0);
        #pragma unroll
        for (int c = 0; c < 8; ++c) { xrv[c] = b2f(x8[c]); at[c] = att[c0 + c]; }
    }
    float dnm = 0.f;
    float acc[8] = {};
    int k = offs[i], ke = offs[i + 1];
    for (; k + 1 < ke; k += 2) {
        int j0 = srcs[k], j1 = srcs[k + 1];
        short8 v80 = *(const short8*)(xlr + (size_t)j0 * 1024 + c0);
        short8 v81 = *(const short8*)(xlr + (size_t)j1 * 1024 + c0);
        float f0[8], f1[8];
        float p0 = 0.f, p1 = 0.f;
        #pragma unroll
        for (int c = 0; c < 8; ++c) {
            f0[c] = b2f(v80[c]);
            float tv = f0[c] + xrv[c];
            p0 = fmaf(at[c], fmaf(0.4f, fabsf(tv), 0.6f * tv), p0);  // leaky 0.2
            f1[c] = b2f(v81[c]);
            float tw = f1[c] + xrv[c];
            p1 = fmaf(at[c], fmaf(0.4f, fabsf(tw), 0.6f * tw), p1);
        }
        p0 += __shfl_xor(p0, 1, 64); p0 += __shfl_xor(p0, 2, 64); p0 += __shfl_xor(p0, 4, 64);
        p1 += __shfl_xor(p1, 1, 64); p1 += __shfl_xor(p1, 2, 64); p1 += __shfl_xor(p1, 4, 64);
        float e0 = __expf(p0), e1 = __expf(p1);
        dnm += e0 + e1;
        #pragma unroll
        for (int c = 0; c < 8; ++c) {
            acc[c] = fmaf(e0, f0[c], acc[c]);
            acc[c] = fmaf(e1, f1[c], acc[c]);
        }
    }
    if (k < ke) {
        int j = srcs[k];
        short8 v8 = *(const short8*)(xlr + (size_t)j * 1024 + c0);
        float f[8], p = 0.f;
        #pragma unroll
        for (int c = 0; c < 8; ++c) {
            f[c] = b2f(v8[c]);
            float tv = f[c] + xrv[c];
            p = fmaf(at[c], fmaf(0.4f, fabsf(tv), 0.6f * tv), p);
        }
        p += __shfl_xor(p, 1, 64); p += __shfl_xor(p, 2, 64); p += __shfl_xor(p, 4, 64);
        float e = __expf(p);
        dnm += e;
        #pragma unroll
        for (int c = 0; c < 8; ++c) acc[c] = fmaf(e, f[c], acc[c]);
    }
    float inv = 1.f / dnm;
    short8 o8;
    #pragma unroll
    for (int c = 0; c < 8; ++c) {
        float o = fmaf(acc[c], inv, bias[c0 + c]);
        o = o > 0.f ? o : __expf(o) - 1.f;             // ELU
        o8[c] = f2b(o);
    }
    *(short8*)(h1 + (size_t)i * 512 + c0) = o8;
}

// ---------------- Layer-2 GATv2 + fused final linear (64->32) + ELU ----------------
__global__ __launch_bounds__(256) void gat_l2_fin(const short* __restrict__ x2,
                        const int* __restrict__ offs, const int* __restrict__ srcs,
                        const float* __restrict__ att, const float* __restrict__ bias,
                        const float* __restrict__ Wlin, const float* __restrict__ blin,
                        float* __restrict__ out, int Nn) {
    __shared__ float Ws[2048];
    __shared__ float bs[32];
    int t = threadIdx.x;
    for (int idx = t; idx < 2048; idx += 256) Ws[idx] = Wlin[idx];
    if (t < 32) bs[t] = blin[t];
    __syncthreads();
    int i = (blockIdx.x * blockDim.x + t) >> 6;
    if (i >= Nn) return;
    int L = t & 63;
    float xrv = b2f(x2[(size_t)i * 128 + 64 + L]);
    float at = att[L];
    float dnm = 0.f, a = 0.f;
    int k = offs[i], ke = offs[i + 1];
    for (; k + 1 < ke; k += 2) {
        int j0 = srcs[k], j1 = srcs[k + 1];
        float v0 = b2f(x2[(size_t)j0 * 128 + L]);
        float v1 = b2f(x2[(size_t)j1 * 128 + L]);
        float tv0 = v0 + xrv, tv1 = v1 + xrv;
        float p0 = at * fmaf(0.4f, fabsf(tv0), 0.6f * tv0);
        float p1 = at * fmaf(0.4f, fabsf(tv1), 0.6f * tv1);
        #pragma unroll
        for (int m = 1; m < 64; m <<= 1) { p0 += __shfl_xor(p0, m, 64); p1 += __shfl_xor(p1, m, 64); }
        float e0 = __expf(p0), e1 = __expf(p1);
        dnm += e0 + e1;
        a = fmaf(e0, v0, a); a = fmaf(e1, v1, a);
    }
    if (k < ke) {
        int j = srcs[k];
        float v = b2f(x2[(size_t)j * 128 + L]);
        float tv = v + xrv;
        float p = at * fmaf(0.4f, fabsf(tv), 0.6f * tv);
        #pragma unroll
        for (int m = 1; m < 64; m <<= 1) p += __shfl_xor(p, m, 64);
        float e = __expf(p);
        dnm += e; a = fmaf(e, v, a);
    }
    float o = a / dnm + bias[L];
    o = o > 0.f ? o : __expf(o) - 1.f;                 // ELU (h2)
    // fused 64->32 linear via lane broadcast
    int oc = L & 31;
    float accl = 0.f;
    #pragma unroll
    for (int kk = 0; kk < 64; ++kk) {
        float ok = __shfl(o, kk, 64);
        accl = fmaf(ok, Ws[kk * 32 + oc], accl);
    }
    if (L < 32) {
        float r = accl + bs[oc];
        r = r > 0.f ? r : __expf(r) - 1.f;
        out[(size_t)i * 32 + oc] = r;
    }
}

extern "C" void kernel_launch(void* const* d_in, const int* in_sizes, int n_in,
                              void* d_out, int out_size, void* d_ws, size_t ws_size,
                              hipStream_t stream) {
    const float* x    = (const float*)d_in[0];
    const int*   ei   = (const int*)d_in[1];
    const float* W1l  = (const float*)d_in[2];
    const float* W1r  = (const float*)d_in[3];
    const float* att1 = (const float*)d_in[4];
    const float* b1   = (const float*)d_in[5];
    const float* W2l  = (const float*)d_in[6];
    const float* W2r  = (const float*)d_in[7];
    const float* att2 = (const float*)d_in[8];
    const float* b2   = (const float*)d_in[9];
    const float* Wlin = (const float*)d_in[10];
    const float* blin = (const float*)d_in[11];

    const int N  = in_sizes[0] / 128;   // 20000
    const int E  = in_sizes[1] / 2;     // 320000
    const int ET = E + N;

    char* w = (char*)d_ws;
    size_t cur = 0;
    auto take = [&](size_t bytes) -> void* {
        void* p = w + cur;
        cur = (cur + bytes + 255) & ~(size_t)255;
        return p;
    };
    int*   counts = (int*)take((size_t)N * 4);
    int*   offs   = (int*)take((size_t)(N + 1) * 4);
    int*   cursor = (int*)take((size_t)N * 4);
    int*   srcs   = (int*)take((size_t)ET * 4);
    short* xb     = (short*)take((size_t)N * 128 * 2);
    short* w1t    = (short*)take((size_t)1024 * 128 * 2);
    short* w2t    = (short*)take((size_t)128 * 512 * 2);
    short* xlr    = (short*)take((size_t)N * 1024 * 2);   // xl1 | xr1
    short* h1     = (short*)take((size_t)N * 512 * 2);
    short* x2     = (short*)take((size_t)N * 128 * 2);    // xl2 | xr2

    hipMemsetAsync(counts, 0, (size_t)N * 4, stream);
    hist_kernel<<<(ET + 255) / 256, 256, 0, stream>>>(ei + E, E, N, counts);
    scan_kernel<<<1, 1024, 0, stream>>>(counts, offs, cursor, N);
    scatter_kernel<<<(ET + 255) / 256, 256, 0, stream>>>(ei, ei + E, E, N, cursor, srcs);

    cvt_f32_bf16<<<(N * 128 + 255) / 256, 256, 0, stream>>>(x, xb, N * 128);
    prep_weights<<<(196608 + 255) / 256, 256, 0, stream>>>(W1l, W1r, W2l, W2r, w1t, w2t);

    gemm1<<<dim3(8, (N + 63) / 64), 256, 0, stream>>>(xb, w1t, xlr, N);
    gat_l1<<<(N + 3) / 4, 256, 0, stream>>>(xlr, offs, srcs, att1, b1, h1, N);

    gemm2<<<(N + 31) / 32, 256, 0, stream>>>(h1, w2t, x2, N);
    gat_l2_fin<<<(N + 3) / 4, 256, 0, stream>>>(x2, offs, srcs, att2, b2, Wlin, blin,
                                                (float*)d_out, N);
}